// Round 4
// baseline (495.560 us; speedup 1.0000x reference)
//
#include <hip/hip_runtime.h>
#include <math.h>

#define C 128
#define SPLIT 4
#define PSTRIDE (C + 4)   // per-partial float stride: [0]=m, [1]=d, [4..131]=acc

typedef float f32x4 __attribute__((ext_vector_type(4)));

// Kernel 1: fused (a) group start offsets from sorted groups, (b) per-group
// attn_vec precompute, (c) zero the per-group arrival counters.
// Blocks [0,nbb) -> bounds scan; [nbb, nbb+b) -> one group each.
__global__ void k_prep(const int* __restrict__ groups, int n, int b, int nbb,
                       const float* __restrict__ node,
                       const float* __restrict__ latent,
                       const float* __restrict__ attn_w,
                       const float* __restrict__ w_w,
                       const float* __restrict__ w_b,
                       const float* __restrict__ f1_w,
                       const float* __restrict__ f1_b,
                       const float* __restrict__ f2_w,
                       const float* __restrict__ f2_b,
                       int* __restrict__ start, float* __restrict__ attnv,
                       int* __restrict__ counter) {
    __shared__ float lds_lat[C];
    __shared__ float red[4];

    if ((int)blockIdx.x < nbb) {
        // ---- bounds scan ----
        int i = blockIdx.x * blockDim.x + threadIdx.x;
        if (i >= n) return;
        int g = groups[i];
        int gp = (i == 0) ? -1 : groups[i - 1];
        for (int gg = gp + 1; gg <= g; ++gg) start[gg] = i;
        if (i == n - 1)
            for (int gg = g + 1; gg <= b; ++gg) start[gg] = n;
        return;
    }

    // ---- per-group attn_vec + counter reset ----
    const int g = blockIdx.x - nbb;
    const int tid = threadIdx.x;
    const int lane = tid & 63;
    const int wv = tid >> 6;

    if (tid == 0) counter[g] = 0;   // visible to k_main via kernel boundary
    if (tid < C) lds_lat[tid] = latent[(size_t)g * C + tid];
    __syncthreads();
    if (tid < C) {
        float ap = node[(size_t)g * C + tid] * w_w[tid];
        float h0 = 0.f, h1 = 0.f;   // split-K for ILP
        #pragma unroll 8
        for (int in = 0; in < C / 2; ++in)
            h0 = fmaf(lds_lat[in], f1_w[in * C + tid], h0);
        #pragma unroll 8
        for (int in = C / 2; in < C; ++in)
            h1 = fmaf(lds_lat[in], f1_w[in * C + tid], h1);
        float h = fmaxf(h0 + h1 + f1_b[tid], 0.f);
        float fp = h * f2_w[tid];
        #pragma unroll
        for (int off = 32; off >= 1; off >>= 1) {
            ap += __shfl_xor(ap, off);
            fp += __shfl_xor(fp, off);
        }
        if (lane == 0) { red[wv * 2] = ap; red[wv * 2 + 1] = fp; }
    }
    __syncthreads();
    if (tid < C) {
        float a_sum = red[0] + red[2];
        float f_sum = red[1] + red[3];
        float alpha = 1.f / (1.f + __expf(-(a_sum + w_b[0])));
        float fout = f_sum + f2_b[0];
        attnv[(size_t)g * C + tid] = alpha * fout + (1.f - alpha) * attn_w[tid];
    }
}

// Main kernel: streaming online-softmax partial + fused last-block merge.
// 4 sub-blocks per group, 256 threads (4 waves). Lanes 0-31 of a wave cover
// one row (float4/lane), lanes 32-63 the next; 8 rows per wave per iter.
__global__ __launch_bounds__(256, 4)
void k_attn_part(const float* __restrict__ node,
                 const float* __restrict__ attnv,
                 const int* __restrict__ start,
                 float* __restrict__ part,
                 int* __restrict__ counter,
                 float* __restrict__ out) {
    const int bid = blockIdx.x;
    const int g = bid >> 2;
    const int q = bid & 3;
    const int tid = threadIdx.x;
    const int lane = tid & 63;
    const int wv = tid >> 6;

    __shared__ float wacc[4][C];
    __shared__ float wm[4], wd[4];
    __shared__ int is_last;

    const int lo = start[g], hi = start[g + 1];
    const int len = hi - lo;
    const int s0 = lo + (len * q) / SPLIT;
    const int s1 = lo + (len * (q + 1)) / SPLIT;

    const int half = lane >> 5;   // which of the 2 rows this half-wave covers
    const int cl = lane & 31;     // channel-lane: channels 4*cl..4*cl+3
    const f32x4 av = *(const f32x4*)&attnv[(size_t)g * C + cl * 4];

    float m = -INFINITY, denom = 0.f;
    f32x4 acc = (f32x4)(0.f);

    for (int base = s0 + wv * 8; base < s1; base += 32) {
        f32x4 r[4];
        #pragma unroll
        for (int j = 0; j < 4; ++j) {
            int row = base + 2 * j + half;
            int rc = row < s1 ? row : (s1 - 1);   // clamp; masked below
            r[j] = __builtin_nontemporal_load(
                       (const f32x4*)&node[(size_t)rc * C + cl * 4]);
        }
        float s[4];
        #pragma unroll
        for (int j = 0; j < 4; ++j)
            s[j] = fmaf(r[j].x, av.x, fmaf(r[j].y, av.y,
                    fmaf(r[j].z, av.z, r[j].w * av.w)));

        // multi-row butterfly reduce: 4 partials over each 32-lane half.
        float k0, k1;
        {
            float ka = (lane & 1) ? s[1] : s[0];
            float sa = (lane & 1) ? s[0] : s[1];
            float kb = (lane & 1) ? s[3] : s[2];
            float sb = (lane & 1) ? s[2] : s[3];
            k0 = ka + __shfl_xor(sa, 1);
            k1 = kb + __shfl_xor(sb, 1);
        }
        float k;
        {
            float ka = (lane & 2) ? k1 : k0;
            float sa = (lane & 2) ? k0 : k1;
            k = ka + __shfl_xor(sa, 2);
        }
        k += __shfl_xor(k, 4);
        k += __shfl_xor(k, 8);
        k += __shfl_xor(k, 16);
        // k = full dot of row (base + 2*(lane&3) + half)
        int rown = base + 2 * (lane & 3) + half;
        k = (rown < s1) ? k : -INFINITY;

        // row max over the 8 distinct rows (bits 0,1,5)
        float mx = k;
        mx = fmaxf(mx, __shfl_xor(mx, 1));
        mx = fmaxf(mx, __shfl_xor(mx, 2));
        mx = fmaxf(mx, __shfl_xor(mx, 32));
        float mb = fmaxf(m, mx);
        float scale = __expf(m - mb);   // m=-inf -> 0, correct
        float p = __expf(k - mb);       // k=-inf -> 0

        float ps = p;
        ps += __shfl_xor(ps, 1);
        ps += __shfl_xor(ps, 2);
        ps += __shfl_xor(ps, 32);
        denom = fmaf(denom, scale, ps);

        // broadcast each row's p (compile-time lane -> v_readlane)
        float pe[4], po[4];
        #pragma unroll
        for (int t = 0; t < 4; ++t) {
            pe[t] = __shfl(p, t);        // row base+2t   (half 0)
            po[t] = __shfl(p, 32 + t);   // row base+2t+1 (half 1)
        }
        acc.x *= scale; acc.y *= scale; acc.z *= scale; acc.w *= scale;
        #pragma unroll
        for (int j = 0; j < 4; ++j) {
            float pj = half ? po[j] : pe[j];
            acc.x = fmaf(pj, r[j].x, acc.x);
            acc.y = fmaf(pj, r[j].y, acc.y);
            acc.z = fmaf(pj, r[j].z, acc.z);
            acc.w = fmaf(pj, r[j].w, acc.w);
        }
        m = mb;
    }

    // fold the two halves (disjoint row sets, same channels)
    acc.x += __shfl_xor(acc.x, 32);
    acc.y += __shfl_xor(acc.y, 32);
    acc.z += __shfl_xor(acc.z, 32);
    acc.w += __shfl_xor(acc.w, 32);

    if (lane == 0) { wm[wv] = m; wd[wv] = denom; }
    if (lane < 32) {
        wacc[wv][cl * 4 + 0] = acc.x;
        wacc[wv][cl * 4 + 1] = acc.y;
        wacc[wv][cl * 4 + 2] = acc.z;
        wacc[wv][cl * 4 + 3] = acc.w;
    }
    __syncthreads();

    // merge 4 wave states -> this block's partial
    if (tid < C) {
        float M = fmaxf(fmaxf(wm[0], wm[1]), fmaxf(wm[2], wm[3]));
        float D = 0.f, A = 0.f;
        #pragma unroll
        for (int w = 0; w < 4; ++w) {
            float sc = (wm[w] == -INFINITY) ? 0.f : __expf(wm[w] - M);
            D = fmaf(wd[w], sc, D);
            A = fmaf(wacc[w][tid], sc, A);
        }
        size_t pb = (size_t)bid * PSTRIDE;
        if (tid == 0) { part[pb] = M; part[pb + 1] = D; }
        part[pb + 4 + tid] = A;
    }

    // ---- last sub-block of the group merges (threadfence reduction) ----
    __threadfence();
    __syncthreads();
    if (tid == 0)
        is_last = (atomicAdd(&counter[g], 1) == SPLIT - 1);
    __syncthreads();
    if (!is_last) return;
    __threadfence();

    if (tid < C) {
        float M = -INFINITY;
        #pragma unroll
        for (int qq = 0; qq < SPLIT; ++qq)
            M = fmaxf(M, part[(size_t)(g * SPLIT + qq) * PSTRIDE]);
        float D = 0.f, A = 0.f;
        #pragma unroll
        for (int qq = 0; qq < SPLIT; ++qq) {
            size_t pb = (size_t)(g * SPLIT + qq) * PSTRIDE;
            float mq = part[pb];
            float sc = (mq == -INFINITY) ? 0.f : __expf(mq - M);
            D = fmaf(part[pb + 1], sc, D);
            A = fmaf(part[pb + 4 + tid], sc, A);
        }
        out[(size_t)g * C + tid] = (D > 0.f) ? (A / D) : 0.f;
    }
}

extern "C" void kernel_launch(void* const* d_in, const int* in_sizes, int n_in,
                              void* d_out, int out_size, void* d_ws, size_t ws_size,
                              hipStream_t stream) {
    const float* node   = (const float*)d_in[0];
    const float* latent = (const float*)d_in[1];
    const float* attn_w = (const float*)d_in[2];
    const float* w_w    = (const float*)d_in[3];
    const float* w_b    = (const float*)d_in[4];
    const float* f1_w   = (const float*)d_in[5];
    const float* f1_b   = (const float*)d_in[6];
    const float* f2_w   = (const float*)d_in[7];
    const float* f2_b   = (const float*)d_in[8];
    const int*   groups = (const int*)d_in[9];

    const int n = in_sizes[9];        // N nodes
    const int b = in_sizes[1] / C;    // number of graphs

    int*   start   = (int*)d_ws;                               // (b+1) ints
    int*   counter = (int*)((char*)d_ws + 4096);               // b ints
    float* attnv   = (float*)((char*)d_ws + 8192);             // b*C floats
    float* part    = (float*)((char*)d_ws + 8192 + 1048576);   // b*SPLIT*PSTRIDE

    const int nbb = (n + 255) / 256;
    k_prep<<<nbb + b, 256, 0, stream>>>(groups, n, b, nbb, node, latent,
                                        attn_w, w_w, w_b, f1_w, f1_b, f2_w, f2_b,
                                        start, attnv, counter);
    k_attn_part<<<b * SPLIT, 256, 0, stream>>>(node, attnv, start, part,
                                               counter, (float*)d_out);
}

// Round 5
// 53.481 us; speedup vs baseline: 9.2661x; 9.2661x over previous
//
#include <hip/hip_runtime.h>
#include <math.h>

#define C 128
#define SPLIT 4
#define PSTRIDE (C + 4)   // per-partial float stride: [0]=m, [1]=d, [4..131]=acc

typedef float f32x4 __attribute__((ext_vector_type(4)));

// Kernel 1: fused (a) group start offsets from the sorted groups array and
// (b) per-group attn_vec precompute. Block ranges: [0, nbb) -> bounds,
// [nbb, nbb+b) -> one group's attn_vec each.
__global__ void k_prep(const int* __restrict__ groups, int n, int b, int nbb,
                       const float* __restrict__ node,
                       const float* __restrict__ latent,
                       const float* __restrict__ attn_w,
                       const float* __restrict__ w_w,
                       const float* __restrict__ w_b,
                       const float* __restrict__ f1_w,
                       const float* __restrict__ f1_b,
                       const float* __restrict__ f2_w,
                       const float* __restrict__ f2_b,
                       int* __restrict__ start, float* __restrict__ attnv) {
    __shared__ float lds_lat[C];
    __shared__ float red[4];

    if ((int)blockIdx.x < nbb) {
        // ---- bounds scan ----
        int i = blockIdx.x * blockDim.x + threadIdx.x;
        if (i >= n) return;
        int g = groups[i];
        int gp = (i == 0) ? -1 : groups[i - 1];
        for (int gg = gp + 1; gg <= g; ++gg) start[gg] = i;
        if (i == n - 1)
            for (int gg = g + 1; gg <= b; ++gg) start[gg] = n;
        return;
    }

    // ---- per-group attn_vec ----
    const int g = blockIdx.x - nbb;
    const int tid = threadIdx.x;
    const int lane = tid & 63;
    const int wv = tid >> 6;

    if (tid < C) lds_lat[tid] = latent[(size_t)g * C + tid];
    __syncthreads();
    if (tid < C) {
        float ap = node[(size_t)g * C + tid] * w_w[tid];
        float h0 = 0.f, h1 = 0.f;   // split-K for ILP on the dependent chain
        #pragma unroll 8
        for (int in = 0; in < C / 2; ++in)
            h0 = fmaf(lds_lat[in], f1_w[in * C + tid], h0);
        #pragma unroll 8
        for (int in = C / 2; in < C; ++in)
            h1 = fmaf(lds_lat[in], f1_w[in * C + tid], h1);
        float h = fmaxf(h0 + h1 + f1_b[tid], 0.f);
        float fp = h * f2_w[tid];
        #pragma unroll
        for (int off = 32; off >= 1; off >>= 1) {
            ap += __shfl_xor(ap, off);
            fp += __shfl_xor(fp, off);
        }
        if (lane == 0) { red[wv * 2] = ap; red[wv * 2 + 1] = fp; }
    }
    __syncthreads();
    if (tid < C) {
        float a_sum = red[0] + red[2];
        float f_sum = red[1] + red[3];
        float alpha = 1.f / (1.f + __expf(-(a_sum + w_b[0])));
        float fout = f_sum + f2_b[0];
        attnv[(size_t)g * C + tid] = alpha * fout + (1.f - alpha) * attn_w[tid];
    }
}

// Main kernel: pure streaming online-softmax reduction. 4 sub-blocks per
// group, 256 threads (4 waves). Lanes 0-31 cover one row (float4/lane),
// lanes 32-63 the next; 8 rows per wave per iteration.
// VGPR=32, LDS=2.5KB -> 8 blocks/CU co-resident (all 2000 blocks in one round).
__global__ __launch_bounds__(256, 8)
void k_attn_part(const float* __restrict__ node,
                 const float* __restrict__ attnv,
                 const int* __restrict__ start,
                 float* __restrict__ part) {
    const int bid = blockIdx.x;
    const int g = bid >> 2;
    const int q = bid & 3;
    const int tid = threadIdx.x;
    const int lane = tid & 63;
    const int wv = tid >> 6;

    __shared__ float wacc[4][C];
    __shared__ float wm[4], wd[4];

    const int lo = start[g], hi = start[g + 1];
    const int len = hi - lo;
    const int s0 = lo + (len * q) / SPLIT;
    const int s1 = lo + (len * (q + 1)) / SPLIT;

    const int half = lane >> 5;   // which of the 2 rows this half-wave covers
    const int cl = lane & 31;     // channel-lane: channels 4*cl..4*cl+3
    const f32x4 av = *(const f32x4*)&attnv[(size_t)g * C + cl * 4];

    float m = -INFINITY, denom = 0.f;
    f32x4 acc = (f32x4)(0.f);

    for (int base = s0 + wv * 8; base < s1; base += 32) {
        f32x4 r[4];
        #pragma unroll
        for (int j = 0; j < 4; ++j) {
            int row = base + 2 * j + half;
            int rc = row < s1 ? row : (s1 - 1);   // clamp; masked below
            r[j] = *(const f32x4*)&node[(size_t)rc * C + cl * 4];
        }
        float s[4];
        #pragma unroll
        for (int j = 0; j < 4; ++j)
            s[j] = fmaf(r[j].x, av.x, fmaf(r[j].y, av.y,
                    fmaf(r[j].z, av.z, r[j].w * av.w)));

        // multi-row butterfly reduce: 4 partials over each 32-lane half.
        float k0, k1;
        {
            float ka = (lane & 1) ? s[1] : s[0];
            float sa = (lane & 1) ? s[0] : s[1];
            float kb = (lane & 1) ? s[3] : s[2];
            float sb = (lane & 1) ? s[2] : s[3];
            k0 = ka + __shfl_xor(sa, 1);
            k1 = kb + __shfl_xor(sb, 1);
        }
        float k;
        {
            float ka = (lane & 2) ? k1 : k0;
            float sa = (lane & 2) ? k0 : k1;
            k = ka + __shfl_xor(sa, 2);
        }
        k += __shfl_xor(k, 4);
        k += __shfl_xor(k, 8);
        k += __shfl_xor(k, 16);
        // k = full dot of row (base + 2*(lane&3) + half)
        int rown = base + 2 * (lane & 3) + half;
        k = (rown < s1) ? k : -INFINITY;

        // row max over the 8 distinct rows (bits 0,1,5)
        float mx = k;
        mx = fmaxf(mx, __shfl_xor(mx, 1));
        mx = fmaxf(mx, __shfl_xor(mx, 2));
        mx = fmaxf(mx, __shfl_xor(mx, 32));
        float mb = fmaxf(m, mx);
        float scale = __expf(m - mb);   // m=-inf -> 0, correct
        float p = __expf(k - mb);       // k=-inf -> 0

        float ps = p;
        ps += __shfl_xor(ps, 1);
        ps += __shfl_xor(ps, 2);
        ps += __shfl_xor(ps, 32);
        denom = fmaf(denom, scale, ps);

        // broadcast each row's p (compile-time lane -> v_readlane)
        float pe[4], po[4];
        #pragma unroll
        for (int t = 0; t < 4; ++t) {
            pe[t] = __shfl(p, t);        // row base+2t   (half 0)
            po[t] = __shfl(p, 32 + t);   // row base+2t+1 (half 1)
        }
        acc.x *= scale; acc.y *= scale; acc.z *= scale; acc.w *= scale;
        #pragma unroll
        for (int j = 0; j < 4; ++j) {
            float pj = half ? po[j] : pe[j];
            acc.x = fmaf(pj, r[j].x, acc.x);
            acc.y = fmaf(pj, r[j].y, acc.y);
            acc.z = fmaf(pj, r[j].z, acc.z);
            acc.w = fmaf(pj, r[j].w, acc.w);
        }
        m = mb;
    }

    // fold the two halves (disjoint row sets, same channels)
    acc.x += __shfl_xor(acc.x, 32);
    acc.y += __shfl_xor(acc.y, 32);
    acc.z += __shfl_xor(acc.z, 32);
    acc.w += __shfl_xor(acc.w, 32);

    if (lane == 0) { wm[wv] = m; wd[wv] = denom; }
    if (lane < 32) {
        wacc[wv][cl * 4 + 0] = acc.x;
        wacc[wv][cl * 4 + 1] = acc.y;
        wacc[wv][cl * 4 + 2] = acc.z;
        wacc[wv][cl * 4 + 3] = acc.w;
    }
    __syncthreads();

    // merge 4 wave states -> one partial per block
    if (tid < C) {
        float M = fmaxf(fmaxf(wm[0], wm[1]), fmaxf(wm[2], wm[3]));
        float D = 0.f, A = 0.f;
        #pragma unroll
        for (int w = 0; w < 4; ++w) {
            float sc = (wm[w] == -INFINITY) ? 0.f : __expf(wm[w] - M);
            D = fmaf(wd[w], sc, D);
            A = fmaf(wacc[w][tid], sc, A);
        }
        size_t pb = (size_t)bid * PSTRIDE;
        if (tid == 0) { part[pb] = M; part[pb + 1] = D; }
        part[pb + 4 + tid] = A;
    }
}

// Merge the 4 sub-block partials per group.
__global__ void k_merge(const float* __restrict__ part, float* __restrict__ out) {
    int g = blockIdx.x;
    int c = threadIdx.x;   // 128 threads
    float M = -INFINITY;
    #pragma unroll
    for (int q = 0; q < SPLIT; ++q)
        M = fmaxf(M, part[(size_t)(g * SPLIT + q) * PSTRIDE]);
    float D = 0.f, A = 0.f;
    #pragma unroll
    for (int q = 0; q < SPLIT; ++q) {
        size_t pb = (size_t)(g * SPLIT + q) * PSTRIDE;
        float mq = part[pb];
        float sc = (mq == -INFINITY) ? 0.f : __expf(mq - M);
        D = fmaf(part[pb + 1], sc, D);
        A = fmaf(part[pb + 4 + c], sc, A);
    }
    out[(size_t)g * C + c] = (D > 0.f) ? (A / D) : 0.f;
}

extern "C" void kernel_launch(void* const* d_in, const int* in_sizes, int n_in,
                              void* d_out, int out_size, void* d_ws, size_t ws_size,
                              hipStream_t stream) {
    const float* node   = (const float*)d_in[0];
    const float* latent = (const float*)d_in[1];
    const float* attn_w = (const float*)d_in[2];
    const float* w_w    = (const float*)d_in[3];
    const float* w_b    = (const float*)d_in[4];
    const float* f1_w   = (const float*)d_in[5];
    const float* f1_b   = (const float*)d_in[6];
    const float* f2_w   = (const float*)d_in[7];
    const float* f2_b   = (const float*)d_in[8];
    const int*   groups = (const int*)d_in[9];

    const int n = in_sizes[9];        // N nodes
    const int b = in_sizes[1] / C;    // number of graphs

    int*   start = (int*)d_ws;                               // (b+1) ints
    float* attnv = (float*)((char*)d_ws + 4096);             // b*C floats
    float* part  = (float*)((char*)d_ws + 4096 + 1048576);   // b*SPLIT*PSTRIDE

    const int nbb = (n + 255) / 256;
    k_prep<<<nbb + b, 256, 0, stream>>>(groups, n, b, nbb, node, latent,
                                        attn_w, w_w, w_b, f1_w, f1_b, f2_w, f2_b,
                                        start, attnv);
    k_attn_part<<<b * SPLIT, 256, 0, stream>>>(node, attnv, start, part);
    k_merge<<<b, C, 0, stream>>>(part, (float*)d_out);
}

// Round 6
// 51.003 us; speedup vs baseline: 9.7162x; 1.0486x over previous
//
#include <hip/hip_runtime.h>
#include <math.h>

#define C 128
#define NW 16   // waves per block in the streaming kernel

typedef float f32x4 __attribute__((ext_vector_type(4)));

// Kernel 1: fused (a) group start offsets from the sorted groups array and
// (b) per-group attn_vec precompute. Block ranges: [0, nbb) -> bounds,
// [nbb, nbb+b) -> one group's attn_vec each.
__global__ void k_prep(const int* __restrict__ groups, int n, int b, int nbb,
                       const float* __restrict__ node,
                       const float* __restrict__ latent,
                       const float* __restrict__ attn_w,
                       const float* __restrict__ w_w,
                       const float* __restrict__ w_b,
                       const float* __restrict__ f1_w,
                       const float* __restrict__ f1_b,
                       const float* __restrict__ f2_w,
                       const float* __restrict__ f2_b,
                       int* __restrict__ start, float* __restrict__ attnv) {
    __shared__ float lds_lat[C];
    __shared__ float red[4];

    if ((int)blockIdx.x < nbb) {
        // ---- bounds scan ----
        int i = blockIdx.x * blockDim.x + threadIdx.x;
        if (i >= n) return;
        int g = groups[i];
        int gp = (i == 0) ? -1 : groups[i - 1];
        for (int gg = gp + 1; gg <= g; ++gg) start[gg] = i;
        if (i == n - 1)
            for (int gg = g + 1; gg <= b; ++gg) start[gg] = n;
        return;
    }

    // ---- per-group attn_vec ----
    const int g = blockIdx.x - nbb;
    const int tid = threadIdx.x;
    const int lane = tid & 63;
    const int wv = tid >> 6;

    if (tid < C) lds_lat[tid] = latent[(size_t)g * C + tid];
    __syncthreads();
    if (tid < C) {
        float ap = node[(size_t)g * C + tid] * w_w[tid];
        float h0 = 0.f, h1 = 0.f;   // split-K for ILP on the dependent chain
        #pragma unroll 8
        for (int in = 0; in < C / 2; ++in)
            h0 = fmaf(lds_lat[in], f1_w[in * C + tid], h0);
        #pragma unroll 8
        for (int in = C / 2; in < C; ++in)
            h1 = fmaf(lds_lat[in], f1_w[in * C + tid], h1);
        float h = fmaxf(h0 + h1 + f1_b[tid], 0.f);
        float fp = h * f2_w[tid];
        #pragma unroll
        for (int off = 32; off >= 1; off >>= 1) {
            ap += __shfl_xor(ap, off);
            fp += __shfl_xor(fp, off);
        }
        if (lane == 0) { red[wv * 2] = ap; red[wv * 2 + 1] = fp; }
    }
    __syncthreads();
    if (tid < C) {
        float a_sum = red[0] + red[2];
        float f_sum = red[1] + red[3];
        float alpha = 1.f / (1.f + __expf(-(a_sum + w_b[0])));
        float fout = f_sum + f2_b[0];
        attnv[(size_t)g * C + tid] = alpha * fout + (1.f - alpha) * attn_w[tid];
    }
}

// Main kernel: one 1024-thread block (16 waves) per group. Streaming
// online-softmax reduction; 16 wave-states merged in LDS; writes out[g]
// directly. No partials, no merge kernel.
// Lanes 0-31 of a wave cover one row (float4/lane), lanes 32-63 the next;
// 8 rows per wave per iteration; 128 rows per block iteration.
__global__ __launch_bounds__(1024, 8)
void k_attn(const float* __restrict__ node,
            const float* __restrict__ attnv,
            const int* __restrict__ start,
            float* __restrict__ out) {
    const int g = blockIdx.x;
    const int tid = threadIdx.x;
    const int lane = tid & 63;
    const int wv = tid >> 6;   // 0..15

    __shared__ float wacc[NW][C];
    __shared__ float wm[NW], wd[NW];

    const int lo = start[g], hi = start[g + 1];

    const int half = lane >> 5;   // which of the 2 rows this half-wave covers
    const int cl = lane & 31;     // channel-lane: channels 4*cl..4*cl+3
    const f32x4 av = *(const f32x4*)&attnv[(size_t)g * C + cl * 4];

    float m = -INFINITY, denom = 0.f;
    f32x4 acc = (f32x4)(0.f);

    for (int base = lo + wv * 8; base < hi; base += NW * 8) {
        f32x4 r[4];
        #pragma unroll
        for (int j = 0; j < 4; ++j) {
            int row = base + 2 * j + half;
            int rc = row < hi ? row : (hi - 1);   // clamp; masked below
            r[j] = *(const f32x4*)&node[(size_t)rc * C + cl * 4];
        }
        float s[4];
        #pragma unroll
        for (int j = 0; j < 4; ++j)
            s[j] = fmaf(r[j].x, av.x, fmaf(r[j].y, av.y,
                    fmaf(r[j].z, av.z, r[j].w * av.w)));

        // multi-row butterfly reduce: 4 partials over each 32-lane half.
        float k0, k1;
        {
            float ka = (lane & 1) ? s[1] : s[0];
            float sa = (lane & 1) ? s[0] : s[1];
            float kb = (lane & 1) ? s[3] : s[2];
            float sb = (lane & 1) ? s[2] : s[3];
            k0 = ka + __shfl_xor(sa, 1);
            k1 = kb + __shfl_xor(sb, 1);
        }
        float k;
        {
            float ka = (lane & 2) ? k1 : k0;
            float sa = (lane & 2) ? k0 : k1;
            k = ka + __shfl_xor(sa, 2);
        }
        k += __shfl_xor(k, 4);
        k += __shfl_xor(k, 8);
        k += __shfl_xor(k, 16);
        // k = full dot of row (base + 2*(lane&3) + half)
        int rown = base + 2 * (lane & 3) + half;
        k = (rown < hi) ? k : -INFINITY;

        // row max over the 8 distinct rows (bits 0,1,5)
        float mx = k;
        mx = fmaxf(mx, __shfl_xor(mx, 1));
        mx = fmaxf(mx, __shfl_xor(mx, 2));
        mx = fmaxf(mx, __shfl_xor(mx, 32));
        float mb = fmaxf(m, mx);
        float scale = __expf(m - mb);   // m=-inf -> 0, correct
        float p = __expf(k - mb);       // k=-inf -> 0

        float ps = p;
        ps += __shfl_xor(ps, 1);
        ps += __shfl_xor(ps, 2);
        ps += __shfl_xor(ps, 32);
        denom = fmaf(denom, scale, ps);

        // broadcast each row's p (compile-time lane -> v_readlane)
        float pe[4], po[4];
        #pragma unroll
        for (int t = 0; t < 4; ++t) {
            pe[t] = __shfl(p, t);        // row base+2t   (half 0)
            po[t] = __shfl(p, 32 + t);   // row base+2t+1 (half 1)
        }
        acc.x *= scale; acc.y *= scale; acc.z *= scale; acc.w *= scale;
        #pragma unroll
        for (int j = 0; j < 4; ++j) {
            float pj = half ? po[j] : pe[j];
            acc.x = fmaf(pj, r[j].x, acc.x);
            acc.y = fmaf(pj, r[j].y, acc.y);
            acc.z = fmaf(pj, r[j].z, acc.z);
            acc.w = fmaf(pj, r[j].w, acc.w);
        }
        m = mb;
    }

    // fold the two halves (disjoint row sets, same channels)
    acc.x += __shfl_xor(acc.x, 32);
    acc.y += __shfl_xor(acc.y, 32);
    acc.z += __shfl_xor(acc.z, 32);
    acc.w += __shfl_xor(acc.w, 32);

    if (lane == 0) { wm[wv] = m; wd[wv] = denom; }
    if (lane < 32) {
        wacc[wv][cl * 4 + 0] = acc.x;
        wacc[wv][cl * 4 + 1] = acc.y;
        wacc[wv][cl * 4 + 2] = acc.z;
        wacc[wv][cl * 4 + 3] = acc.w;
    }
    __syncthreads();

    // merge 16 wave states -> out[g] directly
    if (tid < C) {
        float M = -INFINITY;
        #pragma unroll
        for (int w = 0; w < NW; ++w) M = fmaxf(M, wm[w]);
        float D = 0.f, A = 0.f;
        #pragma unroll
        for (int w = 0; w < NW; ++w) {
            float sc = (wm[w] == -INFINITY) ? 0.f : __expf(wm[w] - M);
            D = fmaf(wd[w], sc, D);
            A = fmaf(wacc[w][tid], sc, A);
        }
        out[(size_t)g * C + tid] = (D > 0.f) ? (A / D) : 0.f;
    }
}

extern "C" void kernel_launch(void* const* d_in, const int* in_sizes, int n_in,
                              void* d_out, int out_size, void* d_ws, size_t ws_size,
                              hipStream_t stream) {
    const float* node   = (const float*)d_in[0];
    const float* latent = (const float*)d_in[1];
    const float* attn_w = (const float*)d_in[2];
    const float* w_w    = (const float*)d_in[3];
    const float* w_b    = (const float*)d_in[4];
    const float* f1_w   = (const float*)d_in[5];
    const float* f1_b   = (const float*)d_in[6];
    const float* f2_w   = (const float*)d_in[7];
    const float* f2_b   = (const float*)d_in[8];
    const int*   groups = (const int*)d_in[9];

    const int n = in_sizes[9];        // N nodes
    const int b = in_sizes[1] / C;    // number of graphs

    int*   start = (int*)d_ws;                     // (b+1) ints
    float* attnv = (float*)((char*)d_ws + 4096);   // b*C floats

    const int nbb = (n + 255) / 256;
    k_prep<<<nbb + b, 256, 0, stream>>>(groups, n, b, nbb, node, latent,
                                        attn_w, w_w, w_b, f1_w, f1_b, f2_w, f2_b,
                                        start, attnv);
    k_attn<<<b, 1024, 0, stream>>>(node, attnv, start, (float*)d_out);
}

// Round 7
// 47.988 us; speedup vs baseline: 10.3268x; 1.0628x over previous
//
#include <hip/hip_runtime.h>
#include <math.h>

#define C 128
#define NW 16        // waves per block
#define NT 1024      // threads per block
#define WIN 8192     // bounds-scan window (positions); >=10 sigma margin

typedef float f32x4 __attribute__((ext_vector_type(4)));

// Single fused kernel: one 1024-thread block (16 waves) per group.
// Prologue: (1) windowed scan of sorted `groups` for [lo,hi) with full-scan
// fallback; (2) in-block 128x128 GEMV -> attn_vec in LDS.
// Main: streaming online-softmax weighted row reduction; 16 wave states
// merged in LDS; writes out[g] directly.
__global__ __launch_bounds__(NT, 8)
void k_attn(const float* __restrict__ node,
            const float* __restrict__ latent,
            const float* __restrict__ attn_w,
            const float* __restrict__ w_w,
            const float* __restrict__ w_b,
            const float* __restrict__ f1_w,
            const float* __restrict__ f1_b,
            const float* __restrict__ f2_w,
            const float* __restrict__ f2_b,
            const int* __restrict__ groups, int n,
            float* __restrict__ out) {
    const int g = blockIdx.x;
    const int B = gridDim.x;
    const int tid = threadIdx.x;
    const int lane = tid & 63;
    const int wv = tid >> 6;   // 0..15

    __shared__ float lds_attn[C];
    __shared__ float lds_lat[C];
    __shared__ float sh_h[8][C];
    __shared__ float red[4];
    __shared__ float wacc[NW][C];
    __shared__ float wm[NW], wd[NW];
    __shared__ int s_lo, s_hi;

    // ---- prologue part 1: bounds via windowed scan ----
    if (tid == 0) { s_lo = (g == 0) ? 0 : -1; s_hi = (g == B - 1) ? n : -1; }
    if (tid < C) lds_lat[tid] = latent[(size_t)g * C + tid];
    __syncthreads();

    {
        const int center = g * (n / B) + (n / B) / 2;
        int wbase = center - WIN / 2;
        if (wbase < 1) wbase = 1;
        // positions wbase + tid + k*NT, k=0..WIN/NT-1 (coalesced)
        #pragma unroll
        for (int k = 0; k < WIN / NT; ++k) {
            int i = wbase + tid + k * NT;
            if (i < n) {
                int gi = groups[i];
                int gp = groups[i - 1];
                if (gp < g && g <= gi) s_lo = i;
                if (gp < g + 1 && g + 1 <= gi) s_hi = i;
            }
        }
        // cheap window edge coverage for i==0 handled by s_lo preset (g==0)
    }

    // ---- prologue part 2: GEMV h = lat @ f1_w (8-way split-K) ----
    {
        const int c = tid & (C - 1);
        const int seg = tid >> 7;            // 0..7, 16 inputs each
        float hp = 0.f;
        #pragma unroll
        for (int in = seg * 16; in < seg * 16 + 16; ++in)
            hp = fmaf(lds_lat[in], f1_w[in * C + c], hp);
        sh_h[seg][c] = hp;
    }
    __syncthreads();

    // fallback: window missed (essentially never) -> full scan
    if (s_lo < 0 || s_hi < 0) {
        for (int i = 1 + tid; i < n; i += NT) {
            int gi = groups[i];
            int gp = groups[i - 1];
            if (gp < g && g <= gi) s_lo = i;
            if (gp < g + 1 && g + 1 <= gi) s_hi = i;
        }
        __syncthreads();
        if (tid == 0) {
            if (s_lo < 0) s_lo = (groups[0] >= g) ? 0 : n;
            if (s_hi < 0) s_hi = (groups[0] >= g + 1) ? 0 : n;
        }
    }

    // ---- prologue part 3: alpha, fout, attn_vec ----
    if (tid < C) {
        float h = sh_h[0][tid] + sh_h[1][tid] + sh_h[2][tid] + sh_h[3][tid]
                + sh_h[4][tid] + sh_h[5][tid] + sh_h[6][tid] + sh_h[7][tid]
                + f1_b[tid];
        h = fmaxf(h, 0.f);
        float fp = h * f2_w[tid];
        float ap = node[(size_t)g * C + tid] * w_w[tid];
        #pragma unroll
        for (int off = 32; off >= 1; off >>= 1) {
            ap += __shfl_xor(ap, off);
            fp += __shfl_xor(fp, off);
        }
        if (lane == 0) { red[wv * 2] = ap; red[wv * 2 + 1] = fp; }
    }
    __syncthreads();
    if (tid < C) {
        float a_sum = red[0] + red[2];
        float f_sum = red[1] + red[3];
        float alpha = 1.f / (1.f + __expf(-(a_sum + w_b[0])));
        float fout = f_sum + f2_b[0];
        lds_attn[tid] = alpha * fout + (1.f - alpha) * attn_w[tid];
    }
    __syncthreads();

    // ---- main: streaming online-softmax reduction ----
    const int lo = s_lo, hi = s_hi;

    const int half = lane >> 5;   // which of the 2 rows this half-wave covers
    const int cl = lane & 31;     // channel-lane: channels 4*cl..4*cl+3
    const f32x4 av = *(const f32x4*)&lds_attn[cl * 4];

    float m = -INFINITY, denom = 0.f;
    f32x4 acc = (f32x4)(0.f);

    for (int base = lo + wv * 8; base < hi; base += NW * 8) {
        f32x4 r[4];
        #pragma unroll
        for (int j = 0; j < 4; ++j) {
            int row = base + 2 * j + half;
            int rc = row < hi ? row : (hi - 1);   // clamp; masked below
            r[j] = *(const f32x4*)&node[(size_t)rc * C + cl * 4];
        }
        float s[4];
        #pragma unroll
        for (int j = 0; j < 4; ++j)
            s[j] = fmaf(r[j].x, av.x, fmaf(r[j].y, av.y,
                    fmaf(r[j].z, av.z, r[j].w * av.w)));

        // multi-row butterfly reduce: 4 partials over each 32-lane half.
        float k0, k1;
        {
            float ka = (lane & 1) ? s[1] : s[0];
            float sa = (lane & 1) ? s[0] : s[1];
            float kb = (lane & 1) ? s[3] : s[2];
            float sb = (lane & 1) ? s[2] : s[3];
            k0 = ka + __shfl_xor(sa, 1);
            k1 = kb + __shfl_xor(sb, 1);
        }
        float k;
        {
            float ka = (lane & 2) ? k1 : k0;
            float sa = (lane & 2) ? k0 : k1;
            k = ka + __shfl_xor(sa, 2);
        }
        k += __shfl_xor(k, 4);
        k += __shfl_xor(k, 8);
        k += __shfl_xor(k, 16);
        // k = full dot of row (base + 2*(lane&3) + half)
        int rown = base + 2 * (lane & 3) + half;
        k = (rown < hi) ? k : -INFINITY;

        // row max over the 8 distinct rows (bits 0,1,5)
        float mx = k;
        mx = fmaxf(mx, __shfl_xor(mx, 1));
        mx = fmaxf(mx, __shfl_xor(mx, 2));
        mx = fmaxf(mx, __shfl_xor(mx, 32));
        float mb = fmaxf(m, mx);
        float scale = __expf(m - mb);   // m=-inf -> 0, correct
        float p = __expf(k - mb);       // k=-inf -> 0

        float ps = p;
        ps += __shfl_xor(ps, 1);
        ps += __shfl_xor(ps, 2);
        ps += __shfl_xor(ps, 32);
        denom = fmaf(denom, scale, ps);

        // broadcast each row's p (compile-time lane -> v_readlane)
        float pe[4], po[4];
        #pragma unroll
        for (int t = 0; t < 4; ++t) {
            pe[t] = __shfl(p, t);        // row base+2t   (half 0)
            po[t] = __shfl(p, 32 + t);   // row base+2t+1 (half 1)
        }
        acc.x *= scale; acc.y *= scale; acc.z *= scale; acc.w *= scale;
        #pragma unroll
        for (int j = 0; j < 4; ++j) {
            float pj = half ? po[j] : pe[j];
            acc.x = fmaf(pj, r[j].x, acc.x);
            acc.y = fmaf(pj, r[j].y, acc.y);
            acc.z = fmaf(pj, r[j].z, acc.z);
            acc.w = fmaf(pj, r[j].w, acc.w);
        }
        m = mb;
    }

    // fold the two halves (disjoint row sets, same channels)
    acc.x += __shfl_xor(acc.x, 32);
    acc.y += __shfl_xor(acc.y, 32);
    acc.z += __shfl_xor(acc.z, 32);
    acc.w += __shfl_xor(acc.w, 32);

    if (lane == 0) { wm[wv] = m; wd[wv] = denom; }
    if (lane < 32) {
        wacc[wv][cl * 4 + 0] = acc.x;
        wacc[wv][cl * 4 + 1] = acc.y;
        wacc[wv][cl * 4 + 2] = acc.z;
        wacc[wv][cl * 4 + 3] = acc.w;
    }
    __syncthreads();

    // merge 16 wave states -> out[g] directly
    if (tid < C) {
        float M = -INFINITY;
        #pragma unroll
        for (int w = 0; w < NW; ++w) M = fmaxf(M, wm[w]);
        float D = 0.f, A = 0.f;
        #pragma unroll
        for (int w = 0; w < NW; ++w) {
            float sc = (wm[w] == -INFINITY) ? 0.f : __expf(wm[w] - M);
            D = fmaf(wd[w], sc, D);
            A = fmaf(wacc[w][tid], sc, A);
        }
        out[(size_t)g * C + tid] = (D > 0.f) ? (A / D) : 0.f;
    }
}

extern "C" void kernel_launch(void* const* d_in, const int* in_sizes, int n_in,
                              void* d_out, int out_size, void* d_ws, size_t ws_size,
                              hipStream_t stream) {
    const float* node   = (const float*)d_in[0];
    const float* latent = (const float*)d_in[1];
    const float* attn_w = (const float*)d_in[2];
    const float* w_w    = (const float*)d_in[3];
    const float* w_b    = (const float*)d_in[4];
    const float* f1_w   = (const float*)d_in[5];
    const float* f1_b   = (const float*)d_in[6];
    const float* f2_w   = (const float*)d_in[7];
    const float* f2_b   = (const float*)d_in[8];
    const int*   groups = (const int*)d_in[9];

    const int n = in_sizes[9];        // N nodes
    const int b = in_sizes[1] / C;    // number of graphs

    k_attn<<<b, NT, 0, stream>>>(node, latent, attn_w, w_w, w_b,
                                 f1_w, f1_b, f2_w, f2_b, groups, n,
                                 (float*)d_out);
}